// Round 19
// baseline (186.963 us; speedup 1.0000x reference)
//
#include <hip/hip_runtime.h>
#include <hip/hip_bf16.h>
#include <float.h>

// Problem constants
#define BB    2
#define NSEQ  2048
#define CDIM  1024
#define HH    16
#define DD    64
#define KKEEP 1228

typedef __attribute__((ext_vector_type(8))) short short8_t;
typedef __attribute__((ext_vector_type(4))) short short4_t;
typedef __attribute__((ext_vector_type(2))) float float2_t;
typedef __attribute__((ext_vector_type(4))) float f32x4;
typedef __attribute__((ext_vector_type(16))) float f32x16;
typedef __attribute__((ext_vector_type(4))) float float4_t;
typedef __attribute__((ext_vector_type(4))) unsigned uint4_t;
typedef __bf16 bf16x8 __attribute__((ext_vector_type(8)));

#define Z16 ((f32x16){0.f,0.f,0.f,0.f,0.f,0.f,0.f,0.f,0.f,0.f,0.f,0.f,0.f,0.f,0.f,0.f})

static __device__ __forceinline__ short f2bf(float x) {
  __hip_bfloat16 h = __float2bfloat16(x);
  short s;
  __builtin_memcpy(&s, &h, 2);
  return s;
}

static __device__ __forceinline__ float bf2f(short s) {
  unsigned u = ((unsigned)(unsigned short)s) << 16;
  float f;
  __builtin_memcpy(&f, &u, 4);
  return f;
}

static __device__ __forceinline__ f32x4 mfma16(bf16x8 a, bf16x8 b, f32x4 c) {
  return __builtin_amdgcn_mfma_f32_16x16x32_bf16(a, b, c, 0, 0, 0);
}

static __device__ __forceinline__ f32x16 mfma32(bf16x8 a, bf16x8 b, f32x16 c) {
  return __builtin_amdgcn_mfma_f32_32x32x16_bf16(a, b, c, 0, 0, 0);
}

static __device__ __forceinline__ void gll16(const void* g, void* l) {
  __builtin_amdgcn_global_load_lds((const __attribute__((address_space(1))) void*)g,
                                   (__attribute__((address_space(3))) void*)l,
                                   16, 0, 0);
}

// slot offset for (tau) in the compact partial table; P(tau)=4/2/3/4
static __device__ __forceinline__ int soff(int tau) {
  if (tau == 0) return 0;
  if (tau < 32) return 4 + (tau - 1) * 2;
  if (tau < 48) return 66 + (tau - 32) * 3;
  return 114 + (tau - 48) * 4;
}
#define SLOTS_PER_BH 178

// ---------------- fused cast kernel (x | W_qkv permute | W_out), one dispatch ----------------
__global__ __launch_bounds__(256) void cast_all_kernel(
    const float* __restrict__ x, const float* __restrict__ wqkv,
    const float* __restrict__ wout, short* __restrict__ xb,
    short* __restrict__ wqkvb, short* __restrict__ woutb) {
  int blk = blockIdx.x;
  if (blk < 4096) {                  // x: 4M f32, 1024 f32/block
    int i = blk * 256 + threadIdx.x;
    float4_t v = ((const float4_t*)x)[i];
    short4_t o;
    o[0] = f2bf(v[0]); o[1] = f2bf(v[1]); o[2] = f2bf(v[2]); o[3] = f2bf(v[3]);
    ((short4_t*)xb)[i] = o;
  } else if (blk < 7168) {           // W_qkv permute: dst row rr <- src row h*192+d*3+c
    int rr = blk - 4096;             // 0..3071
    int c = rr >> 10, hd = rr & 1023;
    int h = hd >> 6, d = hd & 63;
    int srow = h * 192 + d * 3 + c;
    int col = threadIdx.x * 4;
    float4_t v = *(const float4_t*)(wqkv + (size_t)srow * CDIM + col);
    short4_t o;
    o[0] = f2bf(v[0]); o[1] = f2bf(v[1]); o[2] = f2bf(v[2]); o[3] = f2bf(v[3]);
    *(short4_t*)(wqkvb + (size_t)rr * CDIM + col) = o;
  } else {                           // W_out: 1M f32
    int i = (blk - 7168) * 256 + threadIdx.x;
    float4_t v = ((const float4_t*)wout)[i];
    short4_t o;
    o[0] = f2bf(v[0]); o[1] = f2bf(v[1]); o[2] = f2bf(v[2]); o[3] = f2bf(v[3]);
    ((short4_t*)woutb)[i] = o;
  }
}

// ---------------- GEMM: C[M,N] = A[M,K] * B[N,K]^T (both bf16, fp32 acc) ----------------
// EPI==0 scatters q row-major; K,V into PACKED MFMA-fragment-lane layouts:
//   PK[bh][t][s][lane][8]: element (n,d) -> t=n>>5, s=d>>4, lane=(n&31)|((d&8)<<2), j=d&7
//   PV[bh][t][c][lane][8]: element (n,d) -> t=n>>5, c=(d>>5)*2+((n>>4)&1),
//                          lane=(d&31)|((n&8)<<2), j=n&7
template <int EPI>
__global__ __launch_bounds__(256) void gemm_bt_kernel(
    const short* __restrict__ A, const short* __restrict__ B, int K, int N,
    float* __restrict__ outF, short* __restrict__ outQ,
    short* __restrict__ outK, short* __restrict__ outV) {
  __shared__ __align__(16) short lA[128 * 32];
  __shared__ __align__(16) short lB[128 * 32];
  int m0 = blockIdx.y * 128, n0 = blockIdx.x * 128;
  int tid = threadIdx.x, lane = tid & 63;
  int w = tid >> 6;
  int lq = lane & 15, lg = lane >> 4;
  int wm = w >> 1, wn = w & 1;

  f32x4 acc[4][4];
#pragma unroll
  for (int m = 0; m < 4; ++m)
#pragma unroll
    for (int n = 0; n < 4; ++n) acc[m][n] = (f32x4){0.f, 0.f, 0.f, 0.f};

  const int c0 = tid, c1 = tid + 256;
  const short* Ar0 = A + (size_t)(m0 + (c0 >> 2)) * K + (c0 & 3) * 8;
  const short* Ar1 = A + (size_t)(m0 + (c1 >> 2)) * K + (c1 & 3) * 8;
  const short* Br0 = B + (size_t)(n0 + (c0 >> 2)) * K + (c0 & 3) * 8;
  const short* Br1 = B + (size_t)(n0 + (c1 >> 2)) * K + (c1 & 3) * 8;

  for (int k0 = 0; k0 < K; k0 += 32) {
    gll16(Ar0 + k0, lA + c0 * 8);
    gll16(Ar1 + k0, lA + c1 * 8);
    gll16(Br0 + k0, lB + c0 * 8);
    gll16(Br1 + k0, lB + c1 * 8);
    __syncthreads();
    bf16x8 af[4], bf[4];
#pragma unroll
    for (int m = 0; m < 4; ++m)
      af[m] = *(const bf16x8*)(lA + (wm * 64 + m * 16 + lq) * 32 + lg * 8);
#pragma unroll
    for (int n = 0; n < 4; ++n)
      bf[n] = *(const bf16x8*)(lB + (wn * 64 + n * 16 + lq) * 32 + lg * 8);
#pragma unroll
    for (int m = 0; m < 4; ++m)
#pragma unroll
      for (int n = 0; n < 4; ++n) acc[m][n] = mfma16(af[m], bf[n], acc[m][n]);
    __syncthreads();
  }

#pragma unroll
  for (int m = 0; m < 4; ++m)
#pragma unroll
    for (int n = 0; n < 4; ++n) {
      int row_b = m0 + wm * 64 + m * 16 + lg * 4;
      int col = n0 + wn * 64 + n * 16 + lq;
#pragma unroll
      for (int r = 0; r < 4; ++r) {
        float v = acc[m][n][r];
        int row = row_b + r;
        if constexpr (EPI == 1) {
          outF[(size_t)row * N + col] = v;
        } else {
          int c = col >> 10, cc = col & 1023;
          int bb2 = row >> 11, nn = row & 2047;
          int hh2 = cc >> 6, dd2 = cc & 63;
          int bh = bb2 * HH + hh2;
          short val = f2bf(v);
          if (c == 0) {
            outQ[((size_t)bh * NSEQ + nn) * DD + dd2] = val;
          } else if (c == 1) {
            int t = nn >> 5, s = dd2 >> 4;
            int lane2 = (nn & 31) | ((dd2 & 8) << 2);
            outK[(((size_t)bh * 64 + t) * 4 + s) * 512 + lane2 * 8 + (dd2 & 7)] = val;
          } else {
            int t = nn >> 5;
            int c4 = (dd2 >> 5) * 2 + ((nn >> 4) & 1);
            int lane2 = (dd2 & 31) | ((nn & 8) << 2);
            outV[(((size_t)bh * 64 + t) * 4 + c4) * 512 + lane2 * 8 + (nn & 7)] = val;
          }
        }
      }
    }
}

// ---------------- top-k selection -> keep bitmap + jmin (stable: value desc, index asc) ----
__global__ __launch_bounds__(256) void topk_kernel(const int* __restrict__ seq_mask,
                                                   unsigned* __restrict__ keepw,
                                                   int* __restrict__ jminb) {
  __shared__ int hist[10];
  __shared__ int vals[NSEQ];
  __shared__ int seqc[256];
  __shared__ unsigned wbuf[64];
  __shared__ int sT, sNeed, sMin;
  int bh = blockIdx.x, tid = threadIdx.x;
  if (tid < 10) hist[tid] = 0;
  if (tid < 64) wbuf[tid] = 0;
  if (tid == 0) sMin = NSEQ;
  __syncthreads();
  const int* sm = seq_mask + (size_t)bh * NSEQ;
  for (int i = tid; i < NSEQ; i += 256) {
    int v = sm[i];
    vals[i] = v;
    atomicAdd(&hist[v], 1);
  }
  __syncthreads();
  if (tid == 0) {
    int cum = 0, t = 0;
    for (int v = 9; v >= 0; --v) {
      int hv = hist[v];
      if (cum + hv >= KKEEP) { t = v; break; }
      cum += hv;
    }
    sT = t;
    sNeed = KKEEP - cum;   // ties (value==t) kept, lowest indices first
  }
  __syncthreads();
  int t = sT, need = sNeed;
  int base = tid * 8, leq = 0;
  int lv[8];
#pragma unroll
  for (int j = 0; j < 8; ++j) {
    lv[j] = vals[base + j];
    leq += (lv[j] == t);
  }
  seqc[tid] = leq;
  __syncthreads();
  for (int off = 1; off < 256; off <<= 1) {
    int a = 0;
    if (tid >= off) a = seqc[tid - off];
    __syncthreads();
    seqc[tid] += a;
    __syncthreads();
  }
  int eqp = seqc[tid] - leq;  // exclusive prefix of (v==t)
  unsigned mybits = 0;
#pragma unroll
  for (int j = 0; j < 8; ++j) {
    int v = lv[j];
    bool kept = (v > t) || (v == t && eqp < need);
    if (v == t) eqp++;
    if (kept) mybits |= (1u << j);
  }
  atomicOr(&wbuf[tid >> 2], mybits << ((tid & 3) * 8));
  if (mybits) atomicMin(&sMin, base + __ffs(mybits) - 1);
  __syncthreads();
  if (tid < 64) keepw[(size_t)bh * 64 + tid] = wbuf[tid];
  if (tid == 0) jminb[bh] = sMin;
}

// ---------------- flash attention: batch-paired waves, LDS-shared pos_bias ----------------
// Block = (h, tau, part); wave w handles batch b=w (bh = w*16+h). Both waves share the
// same pb[32q x 32k] tile per chunk (LDS double-buffer, one barrier/chunk).
// INTERIOR chunks (t < tau) skip the causal comparison: all keys jj <= kb0c+31 <
// tau*32 <= qglob are statically visible -> pure keep-mask path (saves ~48 VALU
// ops on ~97% of chunks). Diagonal/tail chunks (t >= tau) use the full check
// (tail chunks' always-false check yields -FLT_MAX, preserving the degenerate
// uniform-row semantics exactly).
#define CHUNK32(T, BUF)                                                        \
  do {                                                                         \
    int kb0c = (T) * 32;                                                       \
    const short* kc_ = pkb + (size_t)(T) * 2048 + lane * 8;                    \
    bf16x8 k0 = *(const bf16x8*)(kc_);                                         \
    bf16x8 k1 = *(const bf16x8*)(kc_ + 512);                                   \
    bf16x8 k2 = *(const bf16x8*)(kc_ + 1024);                                  \
    bf16x8 k3 = *(const bf16x8*)(kc_ + 1536);                                  \
    const short* vc_ = pvb + (size_t)(T) * 2048 + lane * 8;                    \
    bf16x8 v00 = *(const bf16x8*)(vc_);                                        \
    bf16x8 v01 = *(const bf16x8*)(vc_ + 512);                                  \
    bf16x8 v10 = *(const bf16x8*)(vc_ + 1024);                                 \
    bf16x8 v11 = *(const bf16x8*)(vc_ + 1536);                                 \
    unsigned kw = kwp[T];                                                      \
    f32x16 s = Z16;                                                            \
    s = mfma32(k0, qf0, s);                                                    \
    s = mfma32(k1, qf1, s);                                                    \
    s = mfma32(k2, qf2, s);                                                    \
    s = mfma32(k3, qf3, s);                                                    \
    float sv[16];                                                              \
    unsigned vb = 0;                                                           \
    float cm = -FLT_MAX;                                                       \
    if ((T) < tau) {  /* interior: causal statically true, keep-mask only */   \
      _Pragma("unroll") for (int g = 0; g < 4; ++g) {                          \
        float2_t pA_ = *(const float2_t*)&ls[BUF][lq32][g * 8 + hi4];          \
        float2_t pB_ = *(const float2_t*)&ls[BUF][lq32][g * 8 + hi4 + 2];      \
        _Pragma("unroll") for (int m = 0; m < 4; ++m) {                        \
          int rr = g * 4 + m;                                                  \
          int kk = m + g * 8 + hi4;                                            \
          float pbv = (m == 0) ? pA_[0] : (m == 1) ? pA_[1]                    \
                    : (m == 2) ? pB_[0] : pB_[1];                              \
          unsigned keep = (kw >> kk) & 1u;                                     \
          float x = keep ? fmaf(s[rr], 0.125f, pbv) : -FLT_MAX;                \
          vb |= keep << rr;                                                    \
          sv[rr] = x;                                                          \
          cm = fmaxf(cm, x);                                                   \
        }                                                                      \
      }                                                                        \
    } else {          /* diagonal / degenerate tail: full causal check */      \
      _Pragma("unroll") for (int g = 0; g < 4; ++g) {                          \
        float2_t pA_ = *(const float2_t*)&ls[BUF][lq32][g * 8 + hi4];          \
        float2_t pB_ = *(const float2_t*)&ls[BUF][lq32][g * 8 + hi4 + 2];      \
        _Pragma("unroll") for (int m = 0; m < 4; ++m) {                        \
          int rr = g * 4 + m;                                                  \
          int kk = m + g * 8 + hi4;                                            \
          int jj = kb0c + kk;                                                  \
          float pbv = (m == 0) ? pA_[0] : (m == 1) ? pA_[1]                    \
                    : (m == 2) ? pB_[0] : pB_[1];                              \
          unsigned keep = (kw >> kk) & 1u;                                     \
          float x = (keep && jj <= qglob) ? fmaf(s[rr], 0.125f, pbv)           \
                                          : -FLT_MAX;                          \
          vb |= keep << rr;                                                    \
          sv[rr] = x;                                                          \
          cm = fmaxf(cm, x);                                                   \
        }                                                                      \
      }                                                                        \
    }                                                                          \
    if (__any(cm > mrun)) {  /* rare: some row's max grew */                   \
      float rm = fmaxf(cm, __shfl_xor(cm, 32));                                \
      float mnew = fmaxf(mrun, rm);                                            \
      float fsc = __expf(mrun - mnew);                                         \
      mrun = mnew;                                                             \
      lsum *= fsc;                                                             \
      _Pragma("unroll") for (int rr = 0; rr < 16; ++rr) {                      \
        int qr = (rr & 3) + 8 * (rr >> 2) + hi4;                               \
        float fr = __shfl(fsc, qr);                                            \
        o0[rr] *= fr;                                                          \
        o1[rr] *= fr;                                                          \
      }                                                                        \
    }                                                                          \
    float pv[16];                                                              \
    float psum = 0.f;                                                          \
    _Pragma("unroll") for (int rr = 0; rr < 16; ++rr) {                        \
      float p_ = ((vb >> rr) & 1u) ? __expf(sv[rr] - mrun) : 0.f;              \
      pv[rr] = p_;                                                             \
      psum += p_;                                                              \
    }                                                                          \
    lsum += psum;                                                              \
    unsigned w0_, w1_, w2_, w3_, w4_, w5_, w6_, w7_;                           \
    asm("v_cvt_pk_bf16_f32 %0, %1, %2" : "=v"(w0_) : "v"(pv[0]), "v"(pv[1]));  \
    asm("v_cvt_pk_bf16_f32 %0, %1, %2" : "=v"(w1_) : "v"(pv[2]), "v"(pv[3]));  \
    asm("v_cvt_pk_bf16_f32 %0, %1, %2" : "=v"(w2_) : "v"(pv[4]), "v"(pv[5]));  \
    asm("v_cvt_pk_bf16_f32 %0, %1, %2" : "=v"(w3_) : "v"(pv[6]), "v"(pv[7]));  \
    asm("v_cvt_pk_bf16_f32 %0, %1, %2" : "=v"(w4_) : "v"(pv[8]), "v"(pv[9]));  \
    asm("v_cvt_pk_bf16_f32 %0, %1, %2" : "=v"(w5_) : "v"(pv[10]), "v"(pv[11]));\
    asm("v_cvt_pk_bf16_f32 %0, %1, %2" : "=v"(w6_) : "v"(pv[12]), "v"(pv[13]));\
    asm("v_cvt_pk_bf16_f32 %0, %1, %2" : "=v"(w7_) : "v"(pv[14]), "v"(pv[15]));\
    asm("v_permlane32_swap_b32 %0, %1" : "+v"(w0_), "+v"(w2_));                \
    asm("v_permlane32_swap_b32 %0, %1" : "+v"(w1_), "+v"(w3_));                \
    asm("v_permlane32_swap_b32 %0, %1" : "+v"(w4_), "+v"(w6_));                \
    asm("v_permlane32_swap_b32 %0, %1" : "+v"(w5_), "+v"(w7_));                \
    uint4_t u0_ = {w0_, w1_, w2_, w3_};                                        \
    uint4_t u1_ = {w4_, w5_, w6_, w7_};                                        \
    bf16x8 pf0 = __builtin_bit_cast(bf16x8, u0_);                              \
    bf16x8 pf1 = __builtin_bit_cast(bf16x8, u1_);                              \
    o0 = mfma32(pf0, v00, o0);                                                 \
    o0 = mfma32(pf1, v01, o0);                                                 \
    o1 = mfma32(pf0, v10, o1);                                                 \
    o1 = mfma32(pf1, v11, o1);                                                 \
  } while (0)

__global__ __launch_bounds__(128) void attn_split_kernel(
    const short* __restrict__ qb, const short* __restrict__ PK,
    const short* __restrict__ PV, const unsigned* __restrict__ keepw,
    const int* __restrict__ jminb, const float* __restrict__ pos_bias,
    short* __restrict__ Opart, float* __restrict__ mlb) {
  __shared__ float ls[2][32][34];   // pb tile double-buffer, pad 34 (2-way aliasing)
  int tid = threadIdx.x;
  int w = tid >> 6, lane = tid & 63;
  int lq32 = lane & 31, hi = lane >> 5;
  int hi4 = hi * 4, hi8 = hi * 8;
  int blk = blockIdx.x;              // 0..2847
  int h = blk & 15;
  int r = blk >> 4;                  // 0..177, heavy-first
  int tau, part;
  if (r < 64)       { tau = 63 - (r >> 2); part = r & 3; }
  else if (r < 112) { int rr = r - 64; tau = 47 - rr / 3; part = rr % 3; }
  else if (r < 116) { tau = 0; part = r - 112; }
  else              { int rr = r - 116; tau = 31 - (rr >> 1); part = rr & 1; }
  int P = (tau == 0 || tau >= 48) ? 4 : (tau >= 32) ? 3 : 2;

  int bh = w * HH + h;               // wave w = batch w
  int q0 = tau << 5;
  int qglob = q0 + lq32;
  int jm0 = jminb[h], jm1 = jminb[HH + h];
  int jmx = (jm0 > jm1) ? jm0 : jm1;
  int nkb = (q0 < jmx) ? 64 : (tau + 1);   // block-uniform range (surplus = masked no-op)
  int t0 = (nkb * part) / P, t1 = (nkb * (part + 1)) / P;

  const short* qp_ = qb + ((size_t)bh * NSEQ + qglob) * DD + hi8;
  bf16x8 qf0 = *(const bf16x8*)(qp_);
  bf16x8 qf1 = *(const bf16x8*)(qp_ + 16);
  bf16x8 qf2 = *(const bf16x8*)(qp_ + 32);
  bf16x8 qf3 = *(const bf16x8*)(qp_ + 48);

  const short* pkb = PK + (size_t)bh * 131072;
  const short* pvb = PV + (size_t)bh * 131072;
  const unsigned* kwp = keepw + (size_t)bh * 64;

  // pb staging: thread covers row srow, cols scol..scol+7 of each 32x32 chunk tile
  int srow = tid >> 2, scol = (tid & 3) * 8;
  const float* pbsrc = pos_bias + ((size_t)h * NSEQ + q0 + srow) * NSEQ + scol;

  float mrun = -FLT_MAX, lsum = 0.f;
  f32x16 o0 = Z16, o1 = Z16;

  if (t0 < t1) {
    {
      float4_t ra0 = *(const float4_t*)(pbsrc + (size_t)t0 * 32);
      float4_t ra1 = *(const float4_t*)(pbsrc + (size_t)t0 * 32 + 4);
      float* lp = &ls[0][srow][scol];
      *(float2_t*)(lp + 0) = (float2_t){ra0[0], ra0[1]};
      *(float2_t*)(lp + 2) = (float2_t){ra0[2], ra0[3]};
      *(float2_t*)(lp + 4) = (float2_t){ra1[0], ra1[1]};
      *(float2_t*)(lp + 6) = (float2_t){ra1[2], ra1[3]};
    }
    int t = t0, buf = 0;
    for (;;) {
      bool more = (t + 1 < t1);
      float4_t rb0, rb1;
      if (more) {
        rb0 = *(const float4_t*)(pbsrc + (size_t)(t + 1) * 32);
        rb1 = *(const float4_t*)(pbsrc + (size_t)(t + 1) * 32 + 4);
      }
      __syncthreads();               // ls[buf] writes (both waves) visible
      CHUNK32(t, buf);
      if (more) {
        float* lp = &ls[buf ^ 1][srow][scol];
        *(float2_t*)(lp + 0) = (float2_t){rb0[0], rb0[1]};
        *(float2_t*)(lp + 2) = (float2_t){rb0[2], rb0[3]};
        *(float2_t*)(lp + 4) = (float2_t){rb1[0], rb1[1]};
        *(float2_t*)(lp + 6) = (float2_t){rb1[2], rb1[3]};
      }
      ++t;
      if (t >= t1) break;
      buf ^= 1;
    }
  }

  float ltot = lsum + __shfl_xor(lsum, 32);   // full row sum per q

  int sidx = bh * SLOTS_PER_BH + soff(tau) + part;
  if (hi == 0) {
    mlb[(size_t)sidx * 64 + lq32] = mrun;
    mlb[(size_t)sidx * 64 + 32 + lq32] = ltot;
  }
  short* op = Opart + (size_t)sidx * 2048;
#pragma unroll
  for (int rr = 0; rr < 16; ++rr) {
    int qr = (rr & 3) + 8 * (rr >> 2) + hi4;
    op[qr * 64 + lq32]      = f2bf(o0[rr]);
    op[qr * 64 + 32 + lq32] = f2bf(o1[rr]);
  }
}

// ---------------- combine partials: all tiles, up to 4 parts ----------------
__global__ __launch_bounds__(64) void combine_kernel(
    const float* __restrict__ mlb, const short* __restrict__ Opart,
    short* __restrict__ attn_out) {
  int blk = blockIdx.x;              // 0..2047
  int bh = blk & 31, tau = blk >> 5; // tau 0..63
  int P = (tau == 0 || tau >= 48) ? 4 : (tau >= 32) ? 3 : 2;
  int s0 = bh * SLOTS_PER_BH + soff(tau);
  int b = bh >> 4, h = bh & 15;
  int lane = threadIdx.x;
  int q = lane >> 1, d0 = (lane & 1) * 32;

  float m[4], l[4];
  float M = -FLT_MAX;
  for (int p = 0; p < P; ++p) {
    m[p] = mlb[(size_t)(s0 + p) * 64 + q];
    l[p] = mlb[(size_t)(s0 + p) * 64 + 32 + q];
    M = fmaxf(M, m[p]);
  }
  float f[4];
  float L = 0.f;
  for (int p = 0; p < P; ++p) {
    f[p] = __expf(m[p] - M);
    L += l[p] * f[p];
  }
  float inv = 1.f / L;

  short* orow = attn_out + ((size_t)b * NSEQ + tau * 32 + q) * CDIM + h * DD + d0;
#pragma unroll
  for (int c = 0; c < 4; ++c) {
    float acc[8] = {0.f, 0.f, 0.f, 0.f, 0.f, 0.f, 0.f, 0.f};
    for (int p = 0; p < P; ++p) {
      short8_t x = *(const short8_t*)(Opart + (size_t)(s0 + p) * 2048 + q * 64 + d0 + c * 8);
#pragma unroll
      for (int jj = 0; jj < 8; ++jj) acc[jj] += f[p] * bf2f(x[jj]);
    }
    short8_t oo;
#pragma unroll
    for (int jj = 0; jj < 8; ++jj) oo[jj] = f2bf(acc[jj] * inv);
    *(short8_t*)(orow + c * 8) = oo;
  }
}

// ---------------- launch ----------------
extern "C" void kernel_launch(void* const* d_in, const int* in_sizes, int n_in,
                              void* d_out, int out_size, void* d_ws, size_t ws_size,
                              hipStream_t stream) {
  const float* x        = (const float*)d_in[0];
  const float* Wqkv     = (const float*)d_in[1];
  const float* Wout     = (const float*)d_in[2];
  const float* pos_bias = (const float*)d_in[3];
  const int*   seq_mask = (const int*)d_in[4];
  float* out = (float*)d_out;

  char* ws = (char*)d_ws;
  short* qb    = (short*)(ws);                          // 0-8 MB   q bf16 [B,H,N,D]
  short* PK    = (short*)(ws + ((size_t)8  << 20));     // 8-16     packed K frags
  short* PV    = (short*)(ws + ((size_t)16 << 20));     // 16-24    packed V frags
  short* woutb = (short*)(ws + ((size_t)24 << 20));     // 24-26    W_out bf16
  short* xb    = (short*)(ws + ((size_t)26 << 20));     // 26-34    x bf16 (dead after GEMM0)
  short* wqkvb = (short*)(ws + ((size_t)34 << 20));     // 34-40    W_qkv bf16 (dead after GEMM0)
  short* Opart = (short*)(ws + ((size_t)26 << 20));     // 26-49.3  partials (overlay xb+wqkvb)
  float* mlb   = (float*)(ws + ((size_t)495 << 17));    // 49.4-50.9 MB  m/l per slot (1.46 MB)
  short* aob   = (short*)(ws + ((size_t)51 << 20));     // 51-59    attn_out bf16
  unsigned* keepw = (unsigned*)(ws + ((size_t)59 << 20) + (512 << 10)); // 59.5 MB
  int* jminb   = (int*)(ws + ((size_t)59 << 20) + (512 << 10) + 65536);

  cast_all_kernel<<<8192, 256, 0, stream>>>(x, Wqkv, Wout, xb, wqkvb, woutb);

  gemm_bt_kernel<0><<<dim3(24, 32), 256, 0, stream>>>(xb, wqkvb, CDIM, 3 * HH * DD,
                                                      nullptr, qb, PK, PV);

  topk_kernel<<<BB * HH, 256, 0, stream>>>(seq_mask, keepw, jminb);

  attn_split_kernel<<<2848, 128, 0, stream>>>(qb, PK, PV, keepw, jminb,
                                              pos_bias, Opart, mlb);

  combine_kernel<<<2048, 64, 0, stream>>>(mlb, Opart, aob);

  gemm_bt_kernel<1><<<dim3(8, 32), 256, 0, stream>>>(aob, woutb, HH * DD, CDIM,
                                                     out, nullptr, nullptr, nullptr);
}

// Round 20
// 173.370 us; speedup vs baseline: 1.0784x; 1.0784x over previous
//
#include <hip/hip_runtime.h>
#include <hip/hip_bf16.h>
#include <float.h>

// Problem constants
#define BB    2
#define NSEQ  2048
#define CDIM  1024
#define HH    16
#define DD    64
#define KKEEP 1228

typedef __attribute__((ext_vector_type(8))) short short8_t;
typedef __attribute__((ext_vector_type(4))) short short4_t;
typedef __attribute__((ext_vector_type(2))) float float2_t;
typedef __attribute__((ext_vector_type(4))) float f32x4;
typedef __attribute__((ext_vector_type(16))) float f32x16;
typedef __attribute__((ext_vector_type(4))) float float4_t;
typedef __attribute__((ext_vector_type(4))) unsigned uint4_t;
typedef __bf16 bf16x8 __attribute__((ext_vector_type(8)));

#define Z16 ((f32x16){0.f,0.f,0.f,0.f,0.f,0.f,0.f,0.f,0.f,0.f,0.f,0.f,0.f,0.f,0.f,0.f})

static __device__ __forceinline__ short f2bf(float x) {
  __hip_bfloat16 h = __float2bfloat16(x);
  short s;
  __builtin_memcpy(&s, &h, 2);
  return s;
}

static __device__ __forceinline__ float bf2f(short s) {
  unsigned u = ((unsigned)(unsigned short)s) << 16;
  float f;
  __builtin_memcpy(&f, &u, 4);
  return f;
}

static __device__ __forceinline__ f32x4 mfma16(bf16x8 a, bf16x8 b, f32x4 c) {
  return __builtin_amdgcn_mfma_f32_16x16x32_bf16(a, b, c, 0, 0, 0);
}

static __device__ __forceinline__ f32x16 mfma32(bf16x8 a, bf16x8 b, f32x16 c) {
  return __builtin_amdgcn_mfma_f32_32x32x16_bf16(a, b, c, 0, 0, 0);
}

static __device__ __forceinline__ void gll16(const void* g, void* l) {
  __builtin_amdgcn_global_load_lds((const __attribute__((address_space(1))) void*)g,
                                   (__attribute__((address_space(3))) void*)l,
                                   16, 0, 0);
}

// slot offset for (tau) in the compact partial table; P(tau)=4/2/3/4
static __device__ __forceinline__ int soff(int tau) {
  if (tau == 0) return 0;
  if (tau < 32) return 4 + (tau - 1) * 2;
  if (tau < 48) return 66 + (tau - 32) * 3;
  return 114 + (tau - 48) * 4;
}
#define SLOTS_PER_BH 178

// ---------------- fused cast kernel (x | W_qkv permute | W_out), one dispatch ----------------
__global__ __launch_bounds__(256) void cast_all_kernel(
    const float* __restrict__ x, const float* __restrict__ wqkv,
    const float* __restrict__ wout, short* __restrict__ xb,
    short* __restrict__ wqkvb, short* __restrict__ woutb) {
  int blk = blockIdx.x;
  if (blk < 4096) {                  // x: 4M f32, 1024 f32/block
    int i = blk * 256 + threadIdx.x;
    float4_t v = ((const float4_t*)x)[i];
    short4_t o;
    o[0] = f2bf(v[0]); o[1] = f2bf(v[1]); o[2] = f2bf(v[2]); o[3] = f2bf(v[3]);
    ((short4_t*)xb)[i] = o;
  } else if (blk < 7168) {           // W_qkv permute: dst row rr <- src row h*192+d*3+c
    int rr = blk - 4096;             // 0..3071
    int c = rr >> 10, hd = rr & 1023;
    int h = hd >> 6, d = hd & 63;
    int srow = h * 192 + d * 3 + c;
    int col = threadIdx.x * 4;
    float4_t v = *(const float4_t*)(wqkv + (size_t)srow * CDIM + col);
    short4_t o;
    o[0] = f2bf(v[0]); o[1] = f2bf(v[1]); o[2] = f2bf(v[2]); o[3] = f2bf(v[3]);
    *(short4_t*)(wqkvb + (size_t)rr * CDIM + col) = o;
  } else {                           // W_out: 1M f32
    int i = (blk - 7168) * 256 + threadIdx.x;
    float4_t v = ((const float4_t*)wout)[i];
    short4_t o;
    o[0] = f2bf(v[0]); o[1] = f2bf(v[1]); o[2] = f2bf(v[2]); o[3] = f2bf(v[3]);
    ((short4_t*)woutb)[i] = o;
  }
}

// ---------------- GEMM: C[M,N] = A[M,K] * B[N,K]^T (both bf16, fp32 acc) ----------------
// EPI==0 scatters q row-major; K,V into PACKED MFMA-fragment-lane layouts:
//   PK[bh][t][s][lane][8]: element (n,d) -> t=n>>5, s=d>>4, lane=(n&31)|((d&8)<<2), j=d&7
//   PV[bh][t][c][lane][8]: element (n,d) -> t=n>>5, c=(d>>5)*2+((n>>4)&1),
//                          lane=(d&31)|((n&8)<<2), j=n&7
template <int EPI>
__global__ __launch_bounds__(256) void gemm_bt_kernel(
    const short* __restrict__ A, const short* __restrict__ B, int K, int N,
    float* __restrict__ outF, short* __restrict__ outQ,
    short* __restrict__ outK, short* __restrict__ outV) {
  __shared__ __align__(16) short lA[128 * 32];
  __shared__ __align__(16) short lB[128 * 32];
  int m0 = blockIdx.y * 128, n0 = blockIdx.x * 128;
  int tid = threadIdx.x, lane = tid & 63;
  int w = tid >> 6;
  int lq = lane & 15, lg = lane >> 4;
  int wm = w >> 1, wn = w & 1;

  f32x4 acc[4][4];
#pragma unroll
  for (int m = 0; m < 4; ++m)
#pragma unroll
    for (int n = 0; n < 4; ++n) acc[m][n] = (f32x4){0.f, 0.f, 0.f, 0.f};

  const int c0 = tid, c1 = tid + 256;
  const short* Ar0 = A + (size_t)(m0 + (c0 >> 2)) * K + (c0 & 3) * 8;
  const short* Ar1 = A + (size_t)(m0 + (c1 >> 2)) * K + (c1 & 3) * 8;
  const short* Br0 = B + (size_t)(n0 + (c0 >> 2)) * K + (c0 & 3) * 8;
  const short* Br1 = B + (size_t)(n0 + (c1 >> 2)) * K + (c1 & 3) * 8;

  for (int k0 = 0; k0 < K; k0 += 32) {
    gll16(Ar0 + k0, lA + c0 * 8);
    gll16(Ar1 + k0, lA + c1 * 8);
    gll16(Br0 + k0, lB + c0 * 8);
    gll16(Br1 + k0, lB + c1 * 8);
    __syncthreads();
    bf16x8 af[4], bf[4];
#pragma unroll
    for (int m = 0; m < 4; ++m)
      af[m] = *(const bf16x8*)(lA + (wm * 64 + m * 16 + lq) * 32 + lg * 8);
#pragma unroll
    for (int n = 0; n < 4; ++n)
      bf[n] = *(const bf16x8*)(lB + (wn * 64 + n * 16 + lq) * 32 + lg * 8);
#pragma unroll
    for (int m = 0; m < 4; ++m)
#pragma unroll
      for (int n = 0; n < 4; ++n) acc[m][n] = mfma16(af[m], bf[n], acc[m][n]);
    __syncthreads();
  }

#pragma unroll
  for (int m = 0; m < 4; ++m)
#pragma unroll
    for (int n = 0; n < 4; ++n) {
      int row_b = m0 + wm * 64 + m * 16 + lg * 4;
      int col = n0 + wn * 64 + n * 16 + lq;
#pragma unroll
      for (int r = 0; r < 4; ++r) {
        float v = acc[m][n][r];
        int row = row_b + r;
        if constexpr (EPI == 1) {
          outF[(size_t)row * N + col] = v;
        } else {
          int c = col >> 10, cc = col & 1023;
          int bb2 = row >> 11, nn = row & 2047;
          int hh2 = cc >> 6, dd2 = cc & 63;
          int bh = bb2 * HH + hh2;
          short val = f2bf(v);
          if (c == 0) {
            outQ[((size_t)bh * NSEQ + nn) * DD + dd2] = val;
          } else if (c == 1) {
            int t = nn >> 5, s = dd2 >> 4;
            int lane2 = (nn & 31) | ((dd2 & 8) << 2);
            outK[(((size_t)bh * 64 + t) * 4 + s) * 512 + lane2 * 8 + (dd2 & 7)] = val;
          } else {
            int t = nn >> 5;
            int c4 = (dd2 >> 5) * 2 + ((nn >> 4) & 1);
            int lane2 = (dd2 & 31) | ((nn & 8) << 2);
            outV[(((size_t)bh * 64 + t) * 4 + c4) * 512 + lane2 * 8 + (nn & 7)] = val;
          }
        }
      }
    }
}

// ---------------- top-k selection -> keep bitmap + jmin (stable: value desc, index asc) ----
__global__ __launch_bounds__(256) void topk_kernel(const int* __restrict__ seq_mask,
                                                   unsigned* __restrict__ keepw,
                                                   int* __restrict__ jminb) {
  __shared__ int hist[10];
  __shared__ int vals[NSEQ];
  __shared__ int seqc[256];
  __shared__ unsigned wbuf[64];
  __shared__ int sT, sNeed, sMin;
  int bh = blockIdx.x, tid = threadIdx.x;
  if (tid < 10) hist[tid] = 0;
  if (tid < 64) wbuf[tid] = 0;
  if (tid == 0) sMin = NSEQ;
  __syncthreads();
  const int* sm = seq_mask + (size_t)bh * NSEQ;
  for (int i = tid; i < NSEQ; i += 256) {
    int v = sm[i];
    vals[i] = v;
    atomicAdd(&hist[v], 1);
  }
  __syncthreads();
  if (tid == 0) {
    int cum = 0, t = 0;
    for (int v = 9; v >= 0; --v) {
      int hv = hist[v];
      if (cum + hv >= KKEEP) { t = v; break; }
      cum += hv;
    }
    sT = t;
    sNeed = KKEEP - cum;   // ties (value==t) kept, lowest indices first
  }
  __syncthreads();
  int t = sT, need = sNeed;
  int base = tid * 8, leq = 0;
  int lv[8];
#pragma unroll
  for (int j = 0; j < 8; ++j) {
    lv[j] = vals[base + j];
    leq += (lv[j] == t);
  }
  seqc[tid] = leq;
  __syncthreads();
  for (int off = 1; off < 256; off <<= 1) {
    int a = 0;
    if (tid >= off) a = seqc[tid - off];
    __syncthreads();
    seqc[tid] += a;
    __syncthreads();
  }
  int eqp = seqc[tid] - leq;  // exclusive prefix of (v==t)
  unsigned mybits = 0;
#pragma unroll
  for (int j = 0; j < 8; ++j) {
    int v = lv[j];
    bool kept = (v > t) || (v == t && eqp < need);
    if (v == t) eqp++;
    if (kept) mybits |= (1u << j);
  }
  atomicOr(&wbuf[tid >> 2], mybits << ((tid & 3) * 8));
  if (mybits) atomicMin(&sMin, base + __ffs(mybits) - 1);
  __syncthreads();
  if (tid < 64) keepw[(size_t)bh * 64 + tid] = wbuf[tid];
  if (tid == 0) jminb[bh] = sMin;
}

// ---------------- flash attention: batch-paired waves, LDS-shared pos_bias ----------------
// Block = (h, tau, part); wave w handles batch b=w (bh = w*16+h). Both waves share the
// same pb[32q x 32k] tile per chunk: staged cooperatively into LDS (double-buffered,
// one barrier/chunk, 128B-contiguous row reads). Both waves iterate the block-uniform
// range from nkb_blk = max over batches; surplus chunks are causally masked no-ops and
// fully-beyond parts (m=-inf, l=0) are annihilated by the combine.
#define CHUNK32(T, BUF)                                                        \
  do {                                                                         \
    int kb0c = (T) * 32;                                                       \
    const short* kc_ = pkb + (size_t)(T) * 2048 + lane * 8;                    \
    bf16x8 k0 = *(const bf16x8*)(kc_);                                         \
    bf16x8 k1 = *(const bf16x8*)(kc_ + 512);                                   \
    bf16x8 k2 = *(const bf16x8*)(kc_ + 1024);                                  \
    bf16x8 k3 = *(const bf16x8*)(kc_ + 1536);                                  \
    const short* vc_ = pvb + (size_t)(T) * 2048 + lane * 8;                    \
    bf16x8 v00 = *(const bf16x8*)(vc_);                                        \
    bf16x8 v01 = *(const bf16x8*)(vc_ + 512);                                  \
    bf16x8 v10 = *(const bf16x8*)(vc_ + 1024);                                 \
    bf16x8 v11 = *(const bf16x8*)(vc_ + 1536);                                 \
    unsigned kw = kwp[T];                                                      \
    f32x16 s = Z16;                                                            \
    s = mfma32(k0, qf0, s);                                                    \
    s = mfma32(k1, qf1, s);                                                    \
    s = mfma32(k2, qf2, s);                                                    \
    s = mfma32(k3, qf3, s);                                                    \
    float sv[16];                                                              \
    unsigned vb = 0;                                                           \
    float cm = -FLT_MAX;                                                       \
    _Pragma("unroll") for (int g = 0; g < 4; ++g) {                            \
      float2_t pA_ = *(const float2_t*)&ls[BUF][lq32][g * 8 + hi4];            \
      float2_t pB_ = *(const float2_t*)&ls[BUF][lq32][g * 8 + hi4 + 2];        \
      _Pragma("unroll") for (int m = 0; m < 4; ++m) {                          \
        int rr = g * 4 + m;                                                    \
        int kk = m + g * 8 + hi4;                                              \
        int jj = kb0c + kk;                                                    \
        float pbv = (m == 0) ? pA_[0] : (m == 1) ? pA_[1]                      \
                  : (m == 2) ? pB_[0] : pB_[1];                                \
        unsigned keep = (kw >> kk) & 1u;                                       \
        float x = (keep && jj <= qglob) ? fmaf(s[rr], 0.125f, pbv)             \
                                        : -FLT_MAX;                            \
        vb |= keep << rr;                                                      \
        sv[rr] = x;                                                            \
        cm = fmaxf(cm, x);                                                     \
      }                                                                        \
    }                                                                          \
    if (__any(cm > mrun)) {  /* rare: some row's max grew */                   \
      float rm = fmaxf(cm, __shfl_xor(cm, 32));                                \
      float mnew = fmaxf(mrun, rm);                                            \
      float fsc = __expf(mrun - mnew);                                         \
      mrun = mnew;                                                             \
      lsum *= fsc;                                                             \
      _Pragma("unroll") for (int rr = 0; rr < 16; ++rr) {                      \
        int qr = (rr & 3) + 8 * (rr >> 2) + hi4;                               \
        float fr = __shfl(fsc, qr);                                            \
        o0[rr] *= fr;                                                          \
        o1[rr] *= fr;                                                          \
      }                                                                        \
    }                                                                          \
    float pv[16];                                                              \
    float psum = 0.f;                                                          \
    _Pragma("unroll") for (int rr = 0; rr < 16; ++rr) {                        \
      float p_ = ((vb >> rr) & 1u) ? __expf(sv[rr] - mrun) : 0.f;              \
      pv[rr] = p_;                                                             \
      psum += p_;                                                              \
    }                                                                          \
    lsum += psum;                                                              \
    unsigned w0_, w1_, w2_, w3_, w4_, w5_, w6_, w7_;                           \
    asm("v_cvt_pk_bf16_f32 %0, %1, %2" : "=v"(w0_) : "v"(pv[0]), "v"(pv[1]));  \
    asm("v_cvt_pk_bf16_f32 %0, %1, %2" : "=v"(w1_) : "v"(pv[2]), "v"(pv[3]));  \
    asm("v_cvt_pk_bf16_f32 %0, %1, %2" : "=v"(w2_) : "v"(pv[4]), "v"(pv[5]));  \
    asm("v_cvt_pk_bf16_f32 %0, %1, %2" : "=v"(w3_) : "v"(pv[6]), "v"(pv[7]));  \
    asm("v_cvt_pk_bf16_f32 %0, %1, %2" : "=v"(w4_) : "v"(pv[8]), "v"(pv[9]));  \
    asm("v_cvt_pk_bf16_f32 %0, %1, %2" : "=v"(w5_) : "v"(pv[10]), "v"(pv[11]));\
    asm("v_cvt_pk_bf16_f32 %0, %1, %2" : "=v"(w6_) : "v"(pv[12]), "v"(pv[13]));\
    asm("v_cvt_pk_bf16_f32 %0, %1, %2" : "=v"(w7_) : "v"(pv[14]), "v"(pv[15]));\
    asm("v_permlane32_swap_b32 %0, %1" : "+v"(w0_), "+v"(w2_));                \
    asm("v_permlane32_swap_b32 %0, %1" : "+v"(w1_), "+v"(w3_));                \
    asm("v_permlane32_swap_b32 %0, %1" : "+v"(w4_), "+v"(w6_));                \
    asm("v_permlane32_swap_b32 %0, %1" : "+v"(w5_), "+v"(w7_));                \
    uint4_t u0_ = {w0_, w1_, w2_, w3_};                                        \
    uint4_t u1_ = {w4_, w5_, w6_, w7_};                                        \
    bf16x8 pf0 = __builtin_bit_cast(bf16x8, u0_);                              \
    bf16x8 pf1 = __builtin_bit_cast(bf16x8, u1_);                              \
    o0 = mfma32(pf0, v00, o0);                                                 \
    o0 = mfma32(pf1, v01, o0);                                                 \
    o1 = mfma32(pf0, v10, o1);                                                 \
    o1 = mfma32(pf1, v11, o1);                                                 \
  } while (0)

__global__ __launch_bounds__(128) void attn_split_kernel(
    const short* __restrict__ qb, const short* __restrict__ PK,
    const short* __restrict__ PV, const unsigned* __restrict__ keepw,
    const int* __restrict__ jminb, const float* __restrict__ pos_bias,
    short* __restrict__ Opart, float* __restrict__ mlb) {
  __shared__ float ls[2][32][34];   // pb tile double-buffer, pad 34 (2-way aliasing)
  int tid = threadIdx.x;
  int w = tid >> 6, lane = tid & 63;
  int lq32 = lane & 31, hi = lane >> 5;
  int hi4 = hi * 4, hi8 = hi * 8;
  int blk = blockIdx.x;              // 0..2847
  int h = blk & 15;
  int r = blk >> 4;                  // 0..177, heavy-first
  int tau, part;
  if (r < 64)       { tau = 63 - (r >> 2); part = r & 3; }
  else if (r < 112) { int rr = r - 64; tau = 47 - rr / 3; part = rr % 3; }
  else if (r < 116) { tau = 0; part = r - 112; }
  else              { int rr = r - 116; tau = 31 - (rr >> 1); part = rr & 1; }
  int P = (tau == 0 || tau >= 48) ? 4 : (tau >= 32) ? 3 : 2;

  int bh = w * HH + h;               // wave w = batch w
  int q0 = tau << 5;
  int qglob = q0 + lq32;
  int jm0 = jminb[h], jm1 = jminb[HH + h];
  int jmx = (jm0 > jm1) ? jm0 : jm1;
  int nkb = (q0 < jmx) ? 64 : (tau + 1);   // block-uniform range (surplus = masked no-op)
  int t0 = (nkb * part) / P, t1 = (nkb * (part + 1)) / P;

  const short* qp_ = qb + ((size_t)bh * NSEQ + qglob) * DD + hi8;
  bf16x8 qf0 = *(const bf16x8*)(qp_);
  bf16x8 qf1 = *(const bf16x8*)(qp_ + 16);
  bf16x8 qf2 = *(const bf16x8*)(qp_ + 32);
  bf16x8 qf3 = *(const bf16x8*)(qp_ + 48);

  const short* pkb = PK + (size_t)bh * 131072;
  const short* pvb = PV + (size_t)bh * 131072;
  const unsigned* kwp = keepw + (size_t)bh * 64;

  // pb staging: thread covers row srow, cols scol..scol+7 of each 32x32 chunk tile
  int srow = tid >> 2, scol = (tid & 3) * 8;
  const float* pbsrc = pos_bias + ((size_t)h * NSEQ + q0 + srow) * NSEQ + scol;

  float mrun = -FLT_MAX, lsum = 0.f;
  f32x16 o0 = Z16, o1 = Z16;

  if (t0 < t1) {
    {
      float4_t ra0 = *(const float4_t*)(pbsrc + (size_t)t0 * 32);
      float4_t ra1 = *(const float4_t*)(pbsrc + (size_t)t0 * 32 + 4);
      float* lp = &ls[0][srow][scol];
      *(float2_t*)(lp + 0) = (float2_t){ra0[0], ra0[1]};
      *(float2_t*)(lp + 2) = (float2_t){ra0[2], ra0[3]};
      *(float2_t*)(lp + 4) = (float2_t){ra1[0], ra1[1]};
      *(float2_t*)(lp + 6) = (float2_t){ra1[2], ra1[3]};
    }
    int t = t0, buf = 0;
    for (;;) {
      bool more = (t + 1 < t1);
      float4_t rb0, rb1;
      if (more) {
        rb0 = *(const float4_t*)(pbsrc + (size_t)(t + 1) * 32);
        rb1 = *(const float4_t*)(pbsrc + (size_t)(t + 1) * 32 + 4);
      }
      __syncthreads();               // ls[buf] writes (both waves) visible
      CHUNK32(t, buf);
      if (more) {
        float* lp = &ls[buf ^ 1][srow][scol];
        *(float2_t*)(lp + 0) = (float2_t){rb0[0], rb0[1]};
        *(float2_t*)(lp + 2) = (float2_t){rb0[2], rb0[3]};
        *(float2_t*)(lp + 4) = (float2_t){rb1[0], rb1[1]};
        *(float2_t*)(lp + 6) = (float2_t){rb1[2], rb1[3]};
      }
      ++t;
      if (t >= t1) break;
      buf ^= 1;
    }
  }

  float ltot = lsum + __shfl_xor(lsum, 32);   // full row sum per q

  int sidx = bh * SLOTS_PER_BH + soff(tau) + part;
  if (hi == 0) {
    mlb[(size_t)sidx * 64 + lq32] = mrun;
    mlb[(size_t)sidx * 64 + 32 + lq32] = ltot;
  }
  short* op = Opart + (size_t)sidx * 2048;
#pragma unroll
  for (int rr = 0; rr < 16; ++rr) {
    int qr = (rr & 3) + 8 * (rr >> 2) + hi4;
    op[qr * 64 + lq32]      = f2bf(o0[rr]);
    op[qr * 64 + 32 + lq32] = f2bf(o1[rr]);
  }
}

// ---------------- combine partials: all tiles, up to 4 parts ----------------
__global__ __launch_bounds__(64) void combine_kernel(
    const float* __restrict__ mlb, const short* __restrict__ Opart,
    short* __restrict__ attn_out) {
  int blk = blockIdx.x;              // 0..2047
  int bh = blk & 31, tau = blk >> 5; // tau 0..63
  int P = (tau == 0 || tau >= 48) ? 4 : (tau >= 32) ? 3 : 2;
  int s0 = bh * SLOTS_PER_BH + soff(tau);
  int b = bh >> 4, h = bh & 15;
  int lane = threadIdx.x;
  int q = lane >> 1, d0 = (lane & 1) * 32;

  float m[4], l[4];
  float M = -FLT_MAX;
  for (int p = 0; p < P; ++p) {
    m[p] = mlb[(size_t)(s0 + p) * 64 + q];
    l[p] = mlb[(size_t)(s0 + p) * 64 + 32 + q];
    M = fmaxf(M, m[p]);
  }
  float f[4];
  float L = 0.f;
  for (int p = 0; p < P; ++p) {
    f[p] = __expf(m[p] - M);
    L += l[p] * f[p];
  }
  float inv = 1.f / L;

  short* orow = attn_out + ((size_t)b * NSEQ + tau * 32 + q) * CDIM + h * DD + d0;
#pragma unroll
  for (int c = 0; c < 4; ++c) {
    float acc[8] = {0.f, 0.f, 0.f, 0.f, 0.f, 0.f, 0.f, 0.f};
    for (int p = 0; p < P; ++p) {
      short8_t x = *(const short8_t*)(Opart + (size_t)(s0 + p) * 2048 + q * 64 + d0 + c * 8);
#pragma unroll
      for (int jj = 0; jj < 8; ++jj) acc[jj] += f[p] * bf2f(x[jj]);
    }
    short8_t oo;
#pragma unroll
    for (int jj = 0; jj < 8; ++jj) oo[jj] = f2bf(acc[jj] * inv);
    *(short8_t*)(orow + c * 8) = oo;
  }
}

// ---------------- launch ----------------
extern "C" void kernel_launch(void* const* d_in, const int* in_sizes, int n_in,
                              void* d_out, int out_size, void* d_ws, size_t ws_size,
                              hipStream_t stream) {
  const float* x        = (const float*)d_in[0];
  const float* Wqkv     = (const float*)d_in[1];
  const float* Wout     = (const float*)d_in[2];
  const float* pos_bias = (const float*)d_in[3];
  const int*   seq_mask = (const int*)d_in[4];
  float* out = (float*)d_out;

  char* ws = (char*)d_ws;
  short* qb    = (short*)(ws);                          // 0-8 MB   q bf16 [B,H,N,D]
  short* PK    = (short*)(ws + ((size_t)8  << 20));     // 8-16     packed K frags
  short* PV    = (short*)(ws + ((size_t)16 << 20));     // 16-24    packed V frags
  short* woutb = (short*)(ws + ((size_t)24 << 20));     // 24-26    W_out bf16
  short* xb    = (short*)(ws + ((size_t)26 << 20));     // 26-34    x bf16 (dead after GEMM0)
  short* wqkvb = (short*)(ws + ((size_t)34 << 20));     // 34-40    W_qkv bf16 (dead after GEMM0)
  short* Opart = (short*)(ws + ((size_t)26 << 20));     // 26-49.3  partials (overlay xb+wqkvb)
  float* mlb   = (float*)(ws + ((size_t)495 << 17));    // 49.4-50.9 MB  m/l per slot (1.46 MB)
  short* aob   = (short*)(ws + ((size_t)51 << 20));     // 51-59    attn_out bf16
  unsigned* keepw = (unsigned*)(ws + ((size_t)59 << 20) + (512 << 10)); // 59.5 MB
  int* jminb   = (int*)(ws + ((size_t)59 << 20) + (512 << 10) + 65536);

  cast_all_kernel<<<8192, 256, 0, stream>>>(x, Wqkv, Wout, xb, wqkvb, woutb);

  gemm_bt_kernel<0><<<dim3(24, 32), 256, 0, stream>>>(xb, wqkvb, CDIM, 3 * HH * DD,
                                                      nullptr, qb, PK, PV);

  topk_kernel<<<BB * HH, 256, 0, stream>>>(seq_mask, keepw, jminb);

  attn_split_kernel<<<2848, 128, 0, stream>>>(qb, PK, PV, keepw, jminb,
                                              pos_bias, Opart, mlb);

  combine_kernel<<<2048, 64, 0, stream>>>(mlb, Opart, aob);

  gemm_bt_kernel<1><<<dim3(8, 32), 256, 0, stream>>>(aob, woutb, HH * DD, CDIM,
                                                     out, nullptr, nullptr, nullptr);
}